// Round 10
// baseline (682.727 us; speedup 1.0000x reference)
//
#include <hip/hip_runtime.h>
#include <cstdint>

typedef __bf16 bf16;
typedef __bf16 bf16x4 __attribute__((ext_vector_type(4)));
typedef __bf16 bf16x8 __attribute__((ext_vector_type(8)));
typedef float  f32x4  __attribute__((ext_vector_type(4)));

#define LOG2E 1.44269504088896340736f

__device__ __forceinline__ f32x4 mfma16(bf16x8 a, bf16x8 b, f32x4 c) {
  return __builtin_amdgcn_mfma_f32_16x16x32_bf16(a, b, c, 0, 0, 0);
}

// async global->LDS, 16B per lane; LDS dest must be wave-uniform base + lane*16
__device__ __forceinline__ void gl2lds16(const bf16* g, bf16* l) {
  __builtin_amdgcn_global_load_lds(
      (const __attribute__((address_space(1))) unsigned int*)g,
      (__attribute__((address_space(3))) unsigned int*)l, 16, 0, 0);
}

// ---------------- convert f32 -> bf16 + zero DKM control area (32 KB) ----------------
__global__ __launch_bounds__(256) void cvt_all(
    const float* __restrict__ x0, const float* __restrict__ w1,
    const float* __restrict__ w2, const float* __restrict__ wip,
    const float* __restrict__ wo,
    bf16* __restrict__ dx0, bf16* __restrict__ dw1, bf16* __restrict__ dw2,
    bf16* __restrict__ dwip, bf16* __restrict__ dwo, float* __restrict__ ctrl)
{
  int i = blockIdx.x * 256 + threadIdx.x;
  if (blockIdx.x == 0) {
    for (int u = threadIdx.x; u < 8192; u += 256) ctrl[u] = 0.f;
  }
  const float* s; bf16* d; int base;
  if      (i <  786432) { s = x0;  d = dx0;  base = 0; }
  else if (i <  933888) { s = w1;  d = dw1;  base = 786432; }
  else if (i < 1081344) { s = w2;  d = dw2;  base = 933888; }
  else if (i < 1523712) { s = wip; d = dwip; base = 1081344; }
  else                  { s = wo;  d = dwo;  base = 1523712; }
  int j = i - base;
  f32x4 v = ((const f32x4*)s)[j];
  bf16x4 r;
  r[0] = (bf16)v[0]; r[1] = (bf16)v[1]; r[2] = (bf16)v[2]; r[3] = (bf16)v[3];
  ((bf16x4*)d)[j] = r;
}

// ---------------- 128x128-tile GEMM: out = act(A[M,768] @ W[N,768]^T + bias) ----------------
template<int RELU, int OUTF32>
__global__ __launch_bounds__(256) void gemm128(
    const bf16* __restrict__ A, const bf16* __restrict__ W,
    const float* __restrict__ bias, bf16* __restrict__ outb,
    float* __restrict__ outf, int N)
{
  __shared__ bf16 Ab[2][8192];   // [128][64]
  __shared__ bf16 Bb[2][8192];
  const int tid = threadIdx.x;
  const int w = tid >> 6, lane = tid & 63;
  const int q2 = lane >> 4, c = lane & 15;
  const int wrow = (w >> 1) * 64, wcol = (w & 1) * 64;
  const int mb = blockIdx.x * 128, nb = blockIdx.y * 128;
  const int srow = tid >> 3, sgrp = tid & 7;

  auto stage = [&](const bf16* __restrict__ src, int rowbase, int kb, bf16* dst) {
#pragma unroll
    for (int i = 0; i < 4; ++i) {
      int row = i * 32 + srow;
      int gs = (sgrp ^ (row & 7)) * 8;
      gl2lds16(src + (size_t)(rowbase + row) * 768 + kb + gs,
               dst + i * 2048 + tid * 8);
    }
  };

  f32x4 acc[4][4] = {};
  stage(A, mb, 0, Ab[0]);
  stage(W, nb, 0, Bb[0]);
  for (int kb = 0; kb < 12; ++kb) {
    const int buf = kb & 1;
    __syncthreads();
    if (kb < 11) {
      stage(A, mb, (kb + 1) * 64, Ab[buf ^ 1]);
      stage(W, nb, (kb + 1) * 64, Bb[buf ^ 1]);
    }
#pragma unroll
    for (int kc = 0; kc < 2; ++kc) {
      bf16x8 af[4], bfr[4];
#pragma unroll
      for (int rt = 0; rt < 4; ++rt) {
        int r = wrow + rt * 16 + c;
        af[rt] = *(const bf16x8*)&Ab[buf][r * 64 + (((kc * 4 + q2) ^ (r & 7)) * 8)];
      }
#pragma unroll
      for (int ct = 0; ct < 4; ++ct) {
        int r = wcol + ct * 16 + c;
        bfr[ct] = *(const bf16x8*)&Bb[buf][r * 64 + (((kc * 4 + q2) ^ (r & 7)) * 8)];
      }
#pragma unroll
      for (int rt = 0; rt < 4; ++rt)
#pragma unroll
        for (int ct = 0; ct < 4; ++ct)
          acc[rt][ct] = mfma16(af[rt], bfr[ct], acc[rt][ct]);
    }
  }
#pragma unroll
  for (int rt = 0; rt < 4; ++rt) {
#pragma unroll
    for (int ct = 0; ct < 4; ++ct) {
      int col = nb + wcol + ct * 16 + c;
      float bv = bias[col];
#pragma unroll
      for (int j = 0; j < 4; ++j) {
        int row = mb + wrow + rt * 16 + q2 * 4 + j;
        float v = acc[rt][ct][j] + bv;
        if (RELU) v = fmaxf(v, 0.f);
        if (OUTF32) outf[(size_t)row * N + col] = v;
        else        outb[(size_t)row * N + col] = (bf16)v;
      }
    }
  }
}

// ---------------- 64x64 tile transpose ----------------
__global__ __launch_bounds__(256) void transpose_bf16(
    const bf16* __restrict__ src, bf16* __restrict__ dst,
    int stride, int colOff, int dstride)
{
  __shared__ bf16 t[64][72];
  const int br = blockIdx.x, bc = blockIdx.y;
  {
    int ir = threadIdx.x >> 2, icb = (threadIdx.x & 3) * 16;
    const bf16* srow = src + (size_t)(br * 64 + ir) * stride + colOff + bc * 64 + icb;
    *(bf16x8*)&t[ir][icb] = *(const bf16x8*)srow;
    *(bf16x8*)&t[ir][icb + 8] = *(const bf16x8*)(srow + 8);
  }
  __syncthreads();
  {
    int oc = threadIdx.x >> 2, orb = (threadIdx.x & 3) * 16;
    bf16x8 v0, v1;
#pragma unroll
    for (int j = 0; j < 8; ++j) { v0[j] = t[orb + j][oc]; v1[j] = t[orb + 8 + j][oc]; }
    bf16* drow = dst + (size_t)(bc * 64 + oc) * dstride + br * 64 + orb;
    *(bf16x8*)drow = v0;
    *(bf16x8*)(drow + 8) = v1;
  }
}

// ---------------- flash attention: 64-row KV tiles, LDS dbuf, no-max softmax ----------------
__global__ __launch_bounds__(256) void attn_kernel(
    const bf16* __restrict__ qkv, const bf16* __restrict__ vt, bf16* __restrict__ o)
{
  const int h = blockIdx.x >> 6;
  const int qt = blockIdx.x & 63;
  const int w = threadIdx.x >> 6, lane = threadIdx.x & 63;
  const int q2 = lane >> 4, c = lane & 15;
  const int qbase = qt * 64 + w * 16;
  __shared__ bf16 Ks[2][64][64];
  __shared__ bf16 Vs[2][64][64];
  __shared__ bf16 Pl[4][16][72];

  const bf16* Qr = qkv + (size_t)(qbase + c) * 2304 + h * 64 + q2 * 8;
  bf16x8 a0 = *(const bf16x8*)(Qr);
  bf16x8 a1 = *(const bf16x8*)(Qr + 32);

  const int srow = lane >> 3;
  const int sg = ((lane & 7) ^ srow) * 8;
  const bf16* kg = qkv + (size_t)(w * 16 + srow) * 2304 + 768 + h * 64 + sg;
  const bf16* vg = vt + (size_t)(h * 64 + w * 16 + srow) * 4096 + sg;

  auto stage = [&](int jt, int buf) {
    const int kvb = jt * 64;
    gl2lds16(kg + (size_t)kvb * 2304,       &Ks[buf][w * 16][0]);
    gl2lds16(kg + (size_t)(kvb + 8) * 2304, &Ks[buf][w * 16 + 8][0]);
    gl2lds16(vg + kvb,                      &Vs[buf][w * 16][0]);
    gl2lds16(vg + kvb + 8 * 4096,           &Vs[buf][w * 16 + 8][0]);
  };

  bf16x8 ones;
#pragma unroll
  for (int i = 0; i < 8; ++i) ones[i] = (bf16)1.0f;

  f32x4 oa[4] = {};
  f32x4 accl = {};
  const int gsw = (q2 ^ (c & 7)) * 8;
  const float SC = 0.125f * LOG2E;

  stage(0, 0);
  for (int jt = 0; jt < 64; ++jt) {
    const int buf = jt & 1;
    __syncthreads();
    if (jt < 63) stage(jt + 1, buf ^ 1);
    f32x4 s[4];
#pragma unroll
    for (int nt = 0; nt < 4; ++nt) {
      const int row = nt * 16 + c;
      bf16x8 b0 = *(const bf16x8*)&Ks[buf][row][gsw];
      bf16x8 b1 = *(const bf16x8*)&Ks[buf][row][gsw ^ 32];
      f32x4 t = {};
      t = mfma16(a0, b0, t);
      t = mfma16(a1, b1, t);
      s[nt] = t;
    }
#pragma unroll
    for (int nt = 0; nt < 4; ++nt)
#pragma unroll
      for (int j = 0; j < 4; ++j)
        Pl[w][q2 * 4 + j][nt * 16 + c] = (bf16)exp2f(s[nt][j] * SC);
    bf16x8 p0 = *(const bf16x8*)(&Pl[w][c][q2 * 8]);
    bf16x8 p1 = *(const bf16x8*)(&Pl[w][c][32 + q2 * 8]);
    accl = mfma16(p0, ones, accl);
    accl = mfma16(p1, ones, accl);
#pragma unroll
    for (int dt = 0; dt < 4; ++dt) {
      const int row = dt * 16 + c;
      bf16x8 v0 = *(const bf16x8*)&Vs[buf][row][gsw];
      bf16x8 v1 = *(const bf16x8*)&Vs[buf][row][gsw ^ 32];
      oa[dt] = mfma16(p0, v0, oa[dt]);
      oa[dt] = mfma16(p1, v1, oa[dt]);
    }
  }
#pragma unroll
  for (int dt = 0; dt < 4; ++dt)
#pragma unroll
    for (int j = 0; j < 4; ++j) {
      int row = qbase + q2 * 4 + j;
      int col = h * 64 + dt * 16 + c;
      o[(size_t)row * 768 + col] = (bf16)(oa[dt][j] / accl[j]);
    }
}

// ---------------- residual + layernorm ----------------
__global__ __launch_bounds__(256) void ln_kernel(
    const float* __restrict__ x0, const float* __restrict__ y,
    const float* __restrict__ g, const float* __restrict__ b,
    float* __restrict__ X, bf16* __restrict__ Xb, float* __restrict__ xn2)
{
  const int w = threadIdx.x >> 6, lane = threadIdx.x & 63;
  const int row = blockIdx.x * 4 + w;
  const float* xr = x0 + (size_t)row * 768;
  const float* yr = y + (size_t)row * 768;
  float z[12]; float s = 0.f;
#pragma unroll
  for (int i = 0; i < 12; ++i) {
    int col = lane + i * 64;
    float zz = 0.5f * xr[col] + 0.5f * yr[col];
    z[i] = zz; s += zz;
  }
#pragma unroll
  for (int off = 32; off; off >>= 1) s += __shfl_xor(s, off, 64);
  float mu = s * (1.f / 768.f);
  float v = 0.f;
#pragma unroll
  for (int i = 0; i < 12; ++i) { float d = z[i] - mu; v += d * d; }
#pragma unroll
  for (int off = 32; off; off >>= 1) v += __shfl_xor(v, off, 64);
  float rstd = rsqrtf(v * (1.f / 768.f) + 1e-5f);
  float sn = 0.f;
#pragma unroll
  for (int i = 0; i < 12; ++i) {
    int col = lane + i * 64;
    float xv = (z[i] - mu) * rstd * g[col] + b[col];
    X[(size_t)row * 768 + col] = xv;
    Xb[(size_t)row * 768 + col] = (bf16)xv;
    sn += xv * xv;
  }
#pragma unroll
  for (int off = 32; off; off >>= 1) sn += __shfl_xor(sn, off, 64);
  if (lane == 0) xn2[row] = sn;
}

// ---------------- grid barrier: monotone counters, split fences (224 blocks) ----------------
__device__ __forceinline__ void gridbar(int* bar, int& ep, int g) {
  __syncthreads();
  if (threadIdx.x == 0) {
    ep++;
    __builtin_amdgcn_fence(__ATOMIC_RELEASE, "agent");
    int v = __hip_atomic_fetch_add(bar + g * 64, 1, __ATOMIC_RELAXED,
                                   __HIP_MEMORY_SCOPE_AGENT) + 1;
    if (v == 28 * ep) {               // 224 blocks / 8 groups = 28
      int tv = __hip_atomic_fetch_add(bar + 512, 1, __ATOMIC_RELAXED,
                                      __HIP_MEMORY_SCOPE_AGENT) + 1;
      if (tv == 8 * ep) {
#pragma unroll
        for (int i = 0; i < 8; ++i)
          __hip_atomic_store(bar + 1024 + i * 64, ep, __ATOMIC_RELAXED,
                             __HIP_MEMORY_SCOPE_AGENT);
      }
    }
    long guard = 0;
    while (__hip_atomic_load(bar + 1024 + g * 64, __ATOMIC_RELAXED,
                             __HIP_MEMORY_SCOPE_AGENT) < ep) {
      __builtin_amdgcn_s_sleep(2);
      if (++guard > (1L << 28)) break;
    }
    __builtin_amdgcn_fence(__ATOMIC_ACQUIRE, "agent");
  }
  __syncthreads();
}

// ---------------- fused DKM, role-split: grid MUST be 224 x 256, dynLDS 128 KB ----------------
// B-role: blocks 0..95 (strip tc=b/2, two cluster-tiles tr={2(b&1), 2(b&1)+1})
// A-role: blocks 96..223 (32 X-rows each)
__global__ __launch_bounds__(256) void dkm_fused(
    const float* __restrict__ XF, const int* __restrict__ idx,
    const bf16* __restrict__ Xb, const float* __restrict__ xn2,
    float* __restrict__ CB, bf16* __restrict__ CBH,
    bf16* __restrict__ aT, float* __restrict__ a_out, float* __restrict__ outC,
    float* __restrict__ asumall, float* __restrict__ cnall,
    float* __restrict__ diffall, int* __restrict__ bar)
{
  extern __shared__ char dynsmem[];
  __shared__ float GsRed[32 * 68];   // Gs[32][68] (A) / red[4][16][16] (B)
  __shared__ float asl[64];
  __shared__ float cnl[16];
  __shared__ float dred[4];
  __shared__ float sdiff;
  float (*Gs)[68] = (float(*)[68])GsRed;
  float (*red)[16][16] = (float(*)[16][16])GsRed;
  const int tid = threadIdx.x;
  const int w = tid >> 6, lane = tid & 63;
  const int q2 = lane >> 4, c = lane & 15;
  const int b = blockIdx.x;
  const int g = b & 7;
  const bool isA = (b >= 96);
  const int tcs = b >> 1;            // B-role strip
  const int trh = (b & 1) * 2;       // B-role tr base
  const int rbase = (b - 96) * 32;   // A-role rows
  int ep = 0;

  bf16* XL  = (bf16*)dynsmem;        // A-role: [32][776]
  bf16* XtL = (bf16*)dynsmem;        // B-role: [16][4096] swizzled

  // ---------- init ----------
  if (isA) {
    int row = tid >> 3, seg = (tid & 7) * 96;
    const bf16* src = Xb + (size_t)(rbase + row) * 768 + seg;
#pragma unroll
    for (int i = 0; i < 12; ++i)
      *(bf16x8*)&XL[row * 776 + seg + i * 8] = *(const bf16x8*)(src + i * 8);
  } else {
    // transposed strip from Xb [4096][768], cols tcs*16..+15 (fused XTB transpose)
    const int h = tid & 1;
    for (int i = 0; i < 32; ++i) {
      int n = i * 128 + (tid >> 1);
      bf16x8 v = *(const bf16x8*)(Xb + (size_t)n * 768 + tcs * 16 + h * 8);
#pragma unroll
      for (int e = 0; e < 8; ++e) {
        int dcol = h * 8 + e;
        XtL[(size_t)dcol * 4096 + (((n >> 3) ^ (dcol & 7)) * 8) + (n & 7)] = v[e];
      }
    }
  }
  if (b < 64) {    // gather C0 = X[idx] (B-role blocks)
    const int src = idx[b];
    float s = 0.f;
#pragma unroll
    for (int u = 0; u < 3; ++u) {
      int d = u * 256 + tid;
      float v = XF[(size_t)src * 768 + d];
      CB[(size_t)b * 768 + d] = v;
      CBH[(size_t)b * 768 + d] = (bf16)v;
      s += v * v;
    }
#pragma unroll
    for (int off = 32; off; off >>= 1) s += __shfl_xor(s, off, 64);
    if (lane == 0) dred[w] = s;
    __syncthreads();
    if (tid == 0) cnall[b] = dred[0] + dred[1] + dred[2] + dred[3];
  }
  const int arow = tid >> 3, asub = tid & 7;   // A-role softmax map: 32 rows x 8 lanes
  const float xn = isA ? xn2[rbase + arow] : 0.f;
  gridbar(bar, ep, g);

  int p = 0;
  for (int t = 0; t < 100; ++t) {
    const int par = t & 1;
    // ================= phase A (blocks 96..223, 32 rows each) =================
    if (isA) {
      const bf16* Cc = CBH + (size_t)par * 49152;
      const float* cnp = cnall + par * 64;
      const bf16* Cr = Cc + (size_t)(w * 16 + c) * 768 + q2 * 8;
      const bf16* X0r = XL + (size_t)c * 776 + q2 * 8;
      const bf16* X1r = XL + (size_t)(16 + c) * 776 + q2 * 8;
      f32x4 g00 = {}, g01 = {}, g10 = {}, g11 = {};
#pragma unroll
      for (int ks = 0; ks < 24; ks += 2) {
        bf16x8 b0 = *(const bf16x8*)(Cr + ks * 32);
        bf16x8 b1 = *(const bf16x8*)(Cr + (ks + 1) * 32);
        g00 = mfma16(*(const bf16x8*)(X0r + ks * 32), b0, g00);
        g10 = mfma16(*(const bf16x8*)(X1r + ks * 32), b0, g10);
        g01 = mfma16(*(const bf16x8*)(X0r + (ks + 1) * 32), b1, g01);
        g11 = mfma16(*(const bf16x8*)(X1r + (ks + 1) * 32), b1, g11);
      }
      f32x4 acc0 = g00 + g01, acc1 = g10 + g11;
      if (tid < 64) asl[tid] = 0.f;
#pragma unroll
      for (int j = 0; j < 4; ++j) {
        Gs[q2 * 4 + j][w * 16 + c] = acc0[j];
        Gs[16 + q2 * 4 + j][w * 16 + c] = acc1[j];
      }
      __syncthreads();
      float lg[8];
#pragma unroll
      for (int u = 0; u < 8; ++u) {
        int col = asub + u * 8;
        float d2 = xn + cnp[col] - 2.f * Gs[arow][col];
        lg[u] = -2.f * sqrtf(fmaxf(d2, 0.f));   // -d/TEMP, TEMP=0.5
      }
      float mx = lg[0];
#pragma unroll
      for (int u = 1; u < 8; ++u) mx = fmaxf(mx, lg[u]);
#pragma unroll
      for (int off = 4; off; off >>= 1) mx = fmaxf(mx, __shfl_xor(mx, off, 8));
      float sum = 0.f;
#pragma unroll
      for (int u = 0; u < 8; ++u) { float e = exp2f((lg[u] - mx) * LOG2E); lg[u] = e; sum += e; }
#pragma unroll
      for (int off = 4; off; off >>= 1) sum += __shfl_xor(sum, off, 8);
      float rs = 1.f / sum;
#pragma unroll
      for (int u = 0; u < 8; ++u) {
        int col = asub + u * 8;
        float av = lg[u] * rs;
        aT[(size_t)col * 4096 + rbase + arow] = (bf16)av;
        atomicAdd(&asl[col], av);
      }
      __syncthreads();
      if (tid < 64) atomicAdd(&asumall[par * 64 + tid], asl[tid]);
    } else if (b == 0) {   // zero next-parity asum/cn during idle phase-A window
      if (tid >= 128 && tid < 192) asumall[(par ^ 1) * 64 + tid - 128] = 0.f;
      else if (tid >= 192)         cnall[(par ^ 1) * 64 + tid - 192] = 0.f;
    }
    gridbar(bar, ep, g);
    // ================= phase B (blocks 0..95, 2 tiles each) =================
    if (!isA) {
#pragma unroll 1
      for (int ti = 0; ti < 2; ++ti) {
        const int tr = trh + ti;
        const bf16* Ar = aT + (size_t)(tr * 16 + c) * 4096 + q2 * 8;
        f32x4 b0 = {}, b1 = {}, b2 = {}, b3 = {};
#pragma unroll
        for (int i = 0; i < 32; i += 4) {
#pragma unroll
          for (int u = 0; u < 4; ++u) {
            int ii = i + u;
            int kb = (w + ii * 4) * 32;
            int gb = (w + ii * 4) * 4 + q2;
            bf16x8 bv = *(const bf16x8*)&XtL[(size_t)c * 4096 + ((gb ^ (c & 7)) * 8)];
            bf16x8 av = *(const bf16x8*)(Ar + kb);
            if (u == 0) b0 = mfma16(av, bv, b0);
            else if (u == 1) b1 = mfma16(av, bv, b1);
            else if (u == 2) b2 = mfma16(av, bv, b2);
            else b3 = mfma16(av, bv, b3);
          }
        }
        f32x4 acc = (b0 + b1) + (b2 + b3);
        __syncthreads();   // red/cnl free from previous tile/iter reads
#pragma unroll
        for (int j = 0; j < 4; ++j) red[w][q2 * 4 + j][c] = acc[j];
        if (tid < 16) cnl[tid] = 0.f;
        __syncthreads();
        const int r = tid >> 4, cl = tid & 15;
        float s = red[0][r][cl] + red[1][r][cl] + red[2][r][cl] + red[3][r][cl];
        const int cluster = tr * 16 + r, dcol = tcs * 16 + cl;
        float denom = asumall[par * 64 + cluster] + 1e-6f;
        float cnew = s / denom;
        size_t cidx = (size_t)cluster * 768 + dcol;
        float cold = CB[(size_t)par * 49152 + cidx];
        CB[(size_t)(par ^ 1) * 49152 + cidx] = cnew;
        CBH[(size_t)(par ^ 1) * 49152 + cidx] = (bf16)cnew;
        atomicAdd(&cnl[r], cnew * cnew);
        float dv = fabsf(cnew - cold);
#pragma unroll
        for (int off = 32; off; off >>= 1) dv += __shfl_xor(dv, off, 64);
        if (lane == 0) dred[w] = dv;
        __syncthreads();
        if (tid < 16)
          atomicAdd(&cnall[(par ^ 1) * 64 + tr * 16 + tid], cnl[tid]);
        if (tid == 0)
          atomicAdd(&diffall[par], dred[0] + dred[1] + dred[2] + dred[3]);
      }
    } else if (b == 223 && tid == 0) {
      diffall[par ^ 1] = 0.f;   // dead slot during phase B
    }
    gridbar(bar, ep, g);
    if (tid == 0)
      sdiff = *(volatile const float*)&diffall[par];
    __syncthreads();
    if (sdiff <= 1e-4f) { p = par; break; }
    p = (t + 1) & 1;
  }
  // ================= final: a_p from C_p (A-role); copy C_p out =================
  if (isA) {
    const bf16* Cc = CBH + (size_t)p * 49152;
    const float* cnp = cnall + p * 64;
    const bf16* Cr = Cc + (size_t)(w * 16 + c) * 768 + q2 * 8;
    const bf16* X0r = XL + (size_t)c * 776 + q2 * 8;
    const bf16* X1r = XL + (size_t)(16 + c) * 776 + q2 * 8;
    f32x4 acc0 = {}, acc1 = {};
#pragma unroll
    for (int ks = 0; ks < 24; ++ks) {
      bf16x8 bb = *(const bf16x8*)(Cr + ks * 32);
      acc0 = mfma16(*(const bf16x8*)(X0r + ks * 32), bb, acc0);
      acc1 = mfma16(*(const bf16x8*)(X1r + ks * 32), bb, acc1);
    }
    __syncthreads();
#pragma unroll
    for (int j = 0; j < 4; ++j) {
      Gs[q2 * 4 + j][w * 16 + c] = acc0[j];
      Gs[16 + q2 * 4 + j][w * 16 + c] = acc1[j];
    }
    __syncthreads();
    float lg[8];
#pragma unroll
    for (int u = 0; u < 8; ++u) {
      int col = asub + u * 8;
      float d2 = xn + cnp[col] - 2.f * Gs[arow][col];
      lg[u] = -2.f * sqrtf(fmaxf(d2, 0.f));
    }
    float mx = lg[0];
#pragma unroll
    for (int u = 1; u < 8; ++u) mx = fmaxf(mx, lg[u]);
#pragma unroll
    for (int off = 4; off; off >>= 1) mx = fmaxf(mx, __shfl_xor(mx, off, 8));
    float sum = 0.f;
#pragma unroll
    for (int u = 0; u < 8; ++u) { float e = exp2f((lg[u] - mx) * LOG2E); lg[u] = e; sum += e; }
#pragma unroll
    for (int off = 4; off; off >>= 1) sum += __shfl_xor(sum, off, 8);
    float rs = 1.f / sum;
#pragma unroll
    for (int u = 0; u < 8; ++u)
      a_out[(size_t)(rbase + arow) * 64 + asub + u * 8] = lg[u] * rs;
  }
  {
    int i = b * 220 + tid;
    if (tid < 220 && i < 49152) outC[i] = CB[(size_t)p * 49152 + i];
  }
}

extern "C" void kernel_launch(void* const* d_in, const int* in_sizes, int n_in,
                              void* d_out, int out_size, void* d_ws, size_t ws_size,
                              hipStream_t stream) {
  const float* x0   = (const float*)d_in[0];
  const float* fc1w = (const float*)d_in[1];
  const float* fc1b = (const float*)d_in[2];
  const float* fc2w = (const float*)d_in[3];
  const float* fc2b = (const float*)d_in[4];
  const float* ipw  = (const float*)d_in[5];
  const float* ipb  = (const float*)d_in[6];
  const float* outw = (const float*)d_in[7];
  const float* outbias = (const float*)d_in[8];
  const float* lng  = (const float*)d_in[9];
  const float* lnb  = (const float*)d_in[10];
  const int*   idx  = (const int*)d_in[11];

  char* p = (char*)d_ws;
  auto take = [&](size_t n) { char* r = p; p += (n + 255) & ~(size_t)255; return r; };
  bf16* X0B   = (bf16*)take((size_t)4096 * 768 * 2);
  bf16* W1B   = (bf16*)take((size_t)768 * 768 * 2);
  bf16* FC2WB = (bf16*)take((size_t)768 * 768 * 2);
  bf16* IPWB  = (bf16*)take((size_t)2304 * 768 * 2);
  bf16* OUTWB = (bf16*)take((size_t)768 * 768 * 2);
  bf16* HB    = (bf16*)take((size_t)4096 * 768 * 2);
  bf16* QKVB  = (bf16*)take((size_t)4096 * 2304 * 2);
  bf16* VT    = (bf16*)take((size_t)768 * 4096 * 2);
  bf16* OB    = (bf16*)take((size_t)4096 * 768 * 2);
  bf16* O2B   = (bf16*)take((size_t)4096 * 768 * 2);
  float* YF   = (float*)take((size_t)4096 * 768 * 4);
  float* XF   = (float*)take((size_t)4096 * 768 * 4);
  bf16* XBB   = (bf16*)take((size_t)4096 * 768 * 2);
  float* XN2  = (float*)take((size_t)4096 * 4);
  float* CB   = (float*)take((size_t)2 * 49152 * 4);
  bf16* CBH   = (bf16*)take((size_t)2 * 49152 * 2);
  bf16* ATB   = (bf16*)take((size_t)64 * 4096 * 2);
  float* CTRLF = (float*)take(8192 * 4);
  float* ASUM = CTRLF;
  float* CN   = CTRLF + 128;
  float* DIFF = CTRLF + 256;
  int* BAR    = (int*)(CTRLF + 512);

  float* aout = (float*)d_out + 49152;

  cvt_all<<<6528, 256, 0, stream>>>(x0, fc1w, fc2w, ipw, outw,
                                    X0B, W1B, FC2WB, IPWB, OUTWB, CTRLF);
  gemm128<1, 0><<<dim3(32, 6), 256, 0, stream>>>(X0B, W1B, fc1b, HB, nullptr, 768);
  gemm128<0, 0><<<dim3(32, 18), 256, 0, stream>>>(HB, IPWB, ipb, QKVB, nullptr, 2304);
  transpose_bf16<<<dim3(64, 12), 256, 0, stream>>>(QKVB, VT, 2304, 1536, 4096);
  attn_kernel<<<768, 256, 0, stream>>>(QKVB, VT, OB);
  gemm128<0, 0><<<dim3(32, 6), 256, 0, stream>>>(OB, OUTWB, outbias, O2B, nullptr, 768);
  gemm128<1, 1><<<dim3(32, 6), 256, 0, stream>>>(O2B, FC2WB, fc2b, nullptr, YF, 768);
  ln_kernel<<<1024, 256, 0, stream>>>(x0, YF, lng, lnb, XF, XBB, XN2);
  dkm_fused<<<224, 256, 131072, stream>>>(XF, idx, XBB, XN2, CB, CBH, ATB, aout,
                                          (float*)d_out, ASUM, CN, DIFF, BAR);
}

// Round 11
// 541.382 us; speedup vs baseline: 1.2611x; 1.2611x over previous
//
#include <hip/hip_runtime.h>
#include <cstdint>

typedef __bf16 bf16;
typedef __bf16 bf16x4 __attribute__((ext_vector_type(4)));
typedef __bf16 bf16x8 __attribute__((ext_vector_type(8)));
typedef float  f32x4  __attribute__((ext_vector_type(4)));

#define LOG2E 1.44269504088896340736f

__device__ __forceinline__ f32x4 mfma16(bf16x8 a, bf16x8 b, f32x4 c) {
  return __builtin_amdgcn_mfma_f32_16x16x32_bf16(a, b, c, 0, 0, 0);
}

// async global->LDS, 16B per lane; LDS dest must be wave-uniform base + lane*16
__device__ __forceinline__ void gl2lds16(const bf16* g, bf16* l) {
  __builtin_amdgcn_global_load_lds(
      (const __attribute__((address_space(1))) unsigned int*)g,
      (__attribute__((address_space(3))) unsigned int*)l, 16, 0, 0);
}

// ---------------- convert f32 -> bf16 + zero DKM control area (32 KB) ----------------
__global__ __launch_bounds__(256) void cvt_all(
    const float* __restrict__ x0, const float* __restrict__ w1,
    const float* __restrict__ w2, const float* __restrict__ wip,
    const float* __restrict__ wo,
    bf16* __restrict__ dx0, bf16* __restrict__ dw1, bf16* __restrict__ dw2,
    bf16* __restrict__ dwip, bf16* __restrict__ dwo, float* __restrict__ ctrl)
{
  int i = blockIdx.x * 256 + threadIdx.x;
  if (blockIdx.x == 0) {
    for (int u = threadIdx.x; u < 8192; u += 256) ctrl[u] = 0.f;
  }
  const float* s; bf16* d; int base;
  if      (i <  786432) { s = x0;  d = dx0;  base = 0; }
  else if (i <  933888) { s = w1;  d = dw1;  base = 786432; }
  else if (i < 1081344) { s = w2;  d = dw2;  base = 933888; }
  else if (i < 1523712) { s = wip; d = dwip; base = 1081344; }
  else                  { s = wo;  d = dwo;  base = 1523712; }
  int j = i - base;
  f32x4 v = ((const f32x4*)s)[j];
  bf16x4 r;
  r[0] = (bf16)v[0]; r[1] = (bf16)v[1]; r[2] = (bf16)v[2]; r[3] = (bf16)v[3];
  ((bf16x4*)d)[j] = r;
}

// ---------------- 128x128-tile GEMM: out = act(A[M,768] @ W[N,768]^T + bias) ----------------
template<int RELU, int OUTF32>
__global__ __launch_bounds__(256) void gemm128(
    const bf16* __restrict__ A, const bf16* __restrict__ W,
    const float* __restrict__ bias, bf16* __restrict__ outb,
    float* __restrict__ outf, int N)
{
  __shared__ bf16 Ab[2][8192];   // [128][64]
  __shared__ bf16 Bb[2][8192];
  const int tid = threadIdx.x;
  const int w = tid >> 6, lane = tid & 63;
  const int q2 = lane >> 4, c = lane & 15;
  const int wrow = (w >> 1) * 64, wcol = (w & 1) * 64;
  const int mb = blockIdx.x * 128, nb = blockIdx.y * 128;
  const int srow = tid >> 3, sgrp = tid & 7;

  auto stage = [&](const bf16* __restrict__ src, int rowbase, int kb, bf16* dst) {
#pragma unroll
    for (int i = 0; i < 4; ++i) {
      int row = i * 32 + srow;
      int gs = (sgrp ^ (row & 7)) * 8;
      gl2lds16(src + (size_t)(rowbase + row) * 768 + kb + gs,
               dst + i * 2048 + tid * 8);
    }
  };

  f32x4 acc[4][4] = {};
  stage(A, mb, 0, Ab[0]);
  stage(W, nb, 0, Bb[0]);
  for (int kb = 0; kb < 12; ++kb) {
    const int buf = kb & 1;
    __syncthreads();
    if (kb < 11) {
      stage(A, mb, (kb + 1) * 64, Ab[buf ^ 1]);
      stage(W, nb, (kb + 1) * 64, Bb[buf ^ 1]);
    }
#pragma unroll
    for (int kc = 0; kc < 2; ++kc) {
      bf16x8 af[4], bfr[4];
#pragma unroll
      for (int rt = 0; rt < 4; ++rt) {
        int r = wrow + rt * 16 + c;
        af[rt] = *(const bf16x8*)&Ab[buf][r * 64 + (((kc * 4 + q2) ^ (r & 7)) * 8)];
      }
#pragma unroll
      for (int ct = 0; ct < 4; ++ct) {
        int r = wcol + ct * 16 + c;
        bfr[ct] = *(const bf16x8*)&Bb[buf][r * 64 + (((kc * 4 + q2) ^ (r & 7)) * 8)];
      }
#pragma unroll
      for (int rt = 0; rt < 4; ++rt)
#pragma unroll
        for (int ct = 0; ct < 4; ++ct)
          acc[rt][ct] = mfma16(af[rt], bfr[ct], acc[rt][ct]);
    }
  }
#pragma unroll
  for (int rt = 0; rt < 4; ++rt) {
#pragma unroll
    for (int ct = 0; ct < 4; ++ct) {
      int col = nb + wcol + ct * 16 + c;
      float bv = bias[col];
#pragma unroll
      for (int j = 0; j < 4; ++j) {
        int row = mb + wrow + rt * 16 + q2 * 4 + j;
        float v = acc[rt][ct][j] + bv;
        if (RELU) v = fmaxf(v, 0.f);
        if (OUTF32) outf[(size_t)row * N + col] = v;
        else        outb[(size_t)row * N + col] = (bf16)v;
      }
    }
  }
}

// ---------------- 64x64 tile transpose ----------------
__global__ __launch_bounds__(256) void transpose_bf16(
    const bf16* __restrict__ src, bf16* __restrict__ dst,
    int stride, int colOff, int dstride)
{
  __shared__ bf16 t[64][72];
  const int br = blockIdx.x, bc = blockIdx.y;
  {
    int ir = threadIdx.x >> 2, icb = (threadIdx.x & 3) * 16;
    const bf16* srow = src + (size_t)(br * 64 + ir) * stride + colOff + bc * 64 + icb;
    *(bf16x8*)&t[ir][icb] = *(const bf16x8*)srow;
    *(bf16x8*)&t[ir][icb + 8] = *(const bf16x8*)(srow + 8);
  }
  __syncthreads();
  {
    int oc = threadIdx.x >> 2, orb = (threadIdx.x & 3) * 16;
    bf16x8 v0, v1;
#pragma unroll
    for (int j = 0; j < 8; ++j) { v0[j] = t[orb + j][oc]; v1[j] = t[orb + 8 + j][oc]; }
    bf16* drow = dst + (size_t)(bc * 64 + oc) * dstride + br * 64 + orb;
    *(bf16x8*)drow = v0;
    *(bf16x8*)(drow + 8) = v1;
  }
}

// ---------------- flash attention: 64-row KV tiles, LDS dbuf, no-max softmax ----------------
__global__ __launch_bounds__(256) void attn_kernel(
    const bf16* __restrict__ qkv, const bf16* __restrict__ vt, bf16* __restrict__ o)
{
  const int h = blockIdx.x >> 6;
  const int qt = blockIdx.x & 63;
  const int w = threadIdx.x >> 6, lane = threadIdx.x & 63;
  const int q2 = lane >> 4, c = lane & 15;
  const int qbase = qt * 64 + w * 16;
  __shared__ bf16 Ks[2][64][64];
  __shared__ bf16 Vs[2][64][64];
  __shared__ bf16 Pl[4][16][72];

  const bf16* Qr = qkv + (size_t)(qbase + c) * 2304 + h * 64 + q2 * 8;
  bf16x8 a0 = *(const bf16x8*)(Qr);
  bf16x8 a1 = *(const bf16x8*)(Qr + 32);

  const int srow = lane >> 3;
  const int sg = ((lane & 7) ^ srow) * 8;
  const bf16* kg = qkv + (size_t)(w * 16 + srow) * 2304 + 768 + h * 64 + sg;
  const bf16* vg = vt + (size_t)(h * 64 + w * 16 + srow) * 4096 + sg;

  auto stage = [&](int jt, int buf) {
    const int kvb = jt * 64;
    gl2lds16(kg + (size_t)kvb * 2304,       &Ks[buf][w * 16][0]);
    gl2lds16(kg + (size_t)(kvb + 8) * 2304, &Ks[buf][w * 16 + 8][0]);
    gl2lds16(vg + kvb,                      &Vs[buf][w * 16][0]);
    gl2lds16(vg + kvb + 8 * 4096,           &Vs[buf][w * 16 + 8][0]);
  };

  bf16x8 ones;
#pragma unroll
  for (int i = 0; i < 8; ++i) ones[i] = (bf16)1.0f;

  f32x4 oa[4] = {};
  f32x4 accl = {};
  const int gsw = (q2 ^ (c & 7)) * 8;
  const float SC = 0.125f * LOG2E;

  stage(0, 0);
  for (int jt = 0; jt < 64; ++jt) {
    const int buf = jt & 1;
    __syncthreads();
    if (jt < 63) stage(jt + 1, buf ^ 1);
    f32x4 s[4];
#pragma unroll
    for (int nt = 0; nt < 4; ++nt) {
      const int row = nt * 16 + c;
      bf16x8 b0 = *(const bf16x8*)&Ks[buf][row][gsw];
      bf16x8 b1 = *(const bf16x8*)&Ks[buf][row][gsw ^ 32];
      f32x4 t = {};
      t = mfma16(a0, b0, t);
      t = mfma16(a1, b1, t);
      s[nt] = t;
    }
#pragma unroll
    for (int nt = 0; nt < 4; ++nt)
#pragma unroll
      for (int j = 0; j < 4; ++j)
        Pl[w][q2 * 4 + j][nt * 16 + c] = (bf16)exp2f(s[nt][j] * SC);
    bf16x8 p0 = *(const bf16x8*)(&Pl[w][c][q2 * 8]);
    bf16x8 p1 = *(const bf16x8*)(&Pl[w][c][32 + q2 * 8]);
    accl = mfma16(p0, ones, accl);
    accl = mfma16(p1, ones, accl);
#pragma unroll
    for (int dt = 0; dt < 4; ++dt) {
      const int row = dt * 16 + c;
      bf16x8 v0 = *(const bf16x8*)&Vs[buf][row][gsw];
      bf16x8 v1 = *(const bf16x8*)&Vs[buf][row][gsw ^ 32];
      oa[dt] = mfma16(p0, v0, oa[dt]);
      oa[dt] = mfma16(p1, v1, oa[dt]);
    }
  }
#pragma unroll
  for (int dt = 0; dt < 4; ++dt)
#pragma unroll
    for (int j = 0; j < 4; ++j) {
      int row = qbase + q2 * 4 + j;
      int col = h * 64 + dt * 16 + c;
      o[(size_t)row * 768 + col] = (bf16)(oa[dt][j] / accl[j]);
    }
}

// ---------------- residual + layernorm ----------------
__global__ __launch_bounds__(256) void ln_kernel(
    const float* __restrict__ x0, const float* __restrict__ y,
    const float* __restrict__ g, const float* __restrict__ b,
    float* __restrict__ X, bf16* __restrict__ Xb, float* __restrict__ xn2)
{
  const int w = threadIdx.x >> 6, lane = threadIdx.x & 63;
  const int row = blockIdx.x * 4 + w;
  const float* xr = x0 + (size_t)row * 768;
  const float* yr = y + (size_t)row * 768;
  float z[12]; float s = 0.f;
#pragma unroll
  for (int i = 0; i < 12; ++i) {
    int col = lane + i * 64;
    float zz = 0.5f * xr[col] + 0.5f * yr[col];
    z[i] = zz; s += zz;
  }
#pragma unroll
  for (int off = 32; off; off >>= 1) s += __shfl_xor(s, off, 64);
  float mu = s * (1.f / 768.f);
  float v = 0.f;
#pragma unroll
  for (int i = 0; i < 12; ++i) { float d = z[i] - mu; v += d * d; }
#pragma unroll
  for (int off = 32; off; off >>= 1) v += __shfl_xor(v, off, 64);
  float rstd = rsqrtf(v * (1.f / 768.f) + 1e-5f);
  float sn = 0.f;
#pragma unroll
  for (int i = 0; i < 12; ++i) {
    int col = lane + i * 64;
    float xv = (z[i] - mu) * rstd * g[col] + b[col];
    X[(size_t)row * 768 + col] = xv;
    Xb[(size_t)row * 768 + col] = (bf16)xv;
    sn += xv * xv;
  }
#pragma unroll
  for (int off = 32; off; off >>= 1) sn += __shfl_xor(sn, off, 64);
  if (lane == 0) xn2[row] = sn;
}

// ---------------- grid barrier: monotone counters, split fences (256 blocks) ----------------
__device__ __forceinline__ void gridbar(int* bar, int& ep, int g) {
  __syncthreads();
  if (threadIdx.x == 0) {
    ep++;
    __builtin_amdgcn_fence(__ATOMIC_RELEASE, "agent");
    int v = __hip_atomic_fetch_add(bar + g * 64, 1, __ATOMIC_RELAXED,
                                   __HIP_MEMORY_SCOPE_AGENT) + 1;
    if (v == 32 * ep) {
      int tv = __hip_atomic_fetch_add(bar + 512, 1, __ATOMIC_RELAXED,
                                      __HIP_MEMORY_SCOPE_AGENT) + 1;
      if (tv == 8 * ep) {
#pragma unroll
        for (int i = 0; i < 8; ++i)
          __hip_atomic_store(bar + 1024 + i * 64, ep, __ATOMIC_RELAXED,
                             __HIP_MEMORY_SCOPE_AGENT);
      }
    }
    long guard = 0;
    while (__hip_atomic_load(bar + 1024 + g * 64, __ATOMIC_RELAXED,
                             __HIP_MEMORY_SCOPE_AGENT) < ep) {
      __builtin_amdgcn_s_sleep(2);
      if (++guard > (1L << 28)) break;
    }
    __builtin_amdgcn_fence(__ATOMIC_ACQUIRE, "agent");
  }
  __syncthreads();
}

// ---------------- fused DKM (R9 structure): grid 256 x 256, dynLDS 128 KB ----------------
__global__ __launch_bounds__(256) void dkm_fused(
    const float* __restrict__ XF, const int* __restrict__ idx,
    const bf16* __restrict__ Xb, const bf16* __restrict__ Xt,
    const float* __restrict__ xn2,
    float* __restrict__ CB, bf16* __restrict__ CBH,
    bf16* __restrict__ aT, float* __restrict__ a_out, float* __restrict__ outC,
    float* __restrict__ asumall, float* __restrict__ cnall,
    float* __restrict__ diffall, int* __restrict__ bar)
{
  extern __shared__ char dynsmem[];
  bf16* XtL = (bf16*)dynsmem;
  __shared__ bf16 XL[16][776];
  __shared__ float GsRed[1024];
  __shared__ float asl[64];
  __shared__ float cnl[16];
  __shared__ float dred[4];
  __shared__ float sdiff;
  float (*Gs)[64] = (float(*)[64])GsRed;
  float (*red)[16][16] = (float(*)[16][16])GsRed;
  const int tid = threadIdx.x;
  const int w = tid >> 6, lane = tid & 63;
  const int q2 = lane >> 4, c = lane & 15;
  const int b = blockIdx.x;
  const int g = b & 7;
  const int rbase = b * 16;
  const int tr = b / 48, tc = b % 48;
  int ep = 0;

  {
    int row = tid >> 4, seg = (tid & 15) * 48;
    const bf16* src = Xb + (size_t)(rbase + row) * 768 + seg;
#pragma unroll
    for (int i = 0; i < 6; ++i)
      *(bf16x8*)&XL[row][seg + i * 8] = *(const bf16x8*)(src + i * 8);
  }
  if (b < 192) {
    const int row = tid >> 4, cc = tid & 15;
    const bf16* XtS = Xt + (size_t)(tc * 16 + row) * 4096;
#pragma unroll
    for (int i = 0; i < 32; ++i) {
      int gg = i * 16 + cc;
      bf16x8 vv = *(const bf16x8*)(XtS + gg * 8);
      *(bf16x8*)&XtL[(size_t)row * 4096 + ((gg ^ (row & 7)) * 8)] = vv;
    }
  }
  if (b < 64) {
    const int src = idx[b];
    float s = 0.f;
#pragma unroll
    for (int u = 0; u < 3; ++u) {
      int d = u * 256 + tid;
      float v = XF[(size_t)src * 768 + d];
      CB[(size_t)b * 768 + d] = v;
      CBH[(size_t)b * 768 + d] = (bf16)v;
      s += v * v;
    }
#pragma unroll
    for (int off = 32; off; off >>= 1) s += __shfl_xor(s, off, 64);
    if (lane == 0) dred[w] = s;
    __syncthreads();
    if (tid == 0) cnall[b] = dred[0] + dred[1] + dred[2] + dred[3];
  }
  const int arow = tid >> 4, aci = tid & 15;
  const float xn = xn2[rbase + arow];
  gridbar(bar, ep, g);

  int p = 0;
  for (int t = 0; t < 100; ++t) {
    const int par = t & 1;
    // ================= phase A =================
    {
      if (b == 0) {
        if (tid >= 128 && tid < 192) asumall[(par ^ 1) * 64 + tid - 128] = 0.f;
        else if (tid >= 192)         cnall[(par ^ 1) * 64 + tid - 192] = 0.f;
      }
      const bf16* C = CBH + (size_t)par * 49152;
      const float* cnp = cnall + par * 64;
      const bf16* Cr = C + (size_t)(w * 16 + c) * 768 + q2 * 8;
      f32x4 a0 = {}, a1 = {}, a2 = {}, a3 = {};
#pragma unroll
      for (int ks = 0; ks < 24; ks += 4) {
        a0 = mfma16(*(const bf16x8*)&XL[c][q2 * 8 + ks * 32],
                    *(const bf16x8*)(Cr + ks * 32), a0);
        a1 = mfma16(*(const bf16x8*)&XL[c][q2 * 8 + (ks + 1) * 32],
                    *(const bf16x8*)(Cr + (ks + 1) * 32), a1);
        a2 = mfma16(*(const bf16x8*)&XL[c][q2 * 8 + (ks + 2) * 32],
                    *(const bf16x8*)(Cr + (ks + 2) * 32), a2);
        a3 = mfma16(*(const bf16x8*)&XL[c][q2 * 8 + (ks + 3) * 32],
                    *(const bf16x8*)(Cr + (ks + 3) * 32), a3);
      }
      f32x4 acc = (a0 + a1) + (a2 + a3);
      if (tid < 64) asl[tid] = 0.f;
#pragma unroll
      for (int j = 0; j < 4; ++j) Gs[q2 * 4 + j][w * 16 + c] = acc[j];
      __syncthreads();
      float lg[4];
#pragma unroll
      for (int u = 0; u < 4; ++u) {
        int col = aci + u * 16;
        float d2 = xn + cnp[col] - 2.f * Gs[arow][col];
        lg[u] = -2.f * sqrtf(fmaxf(d2, 0.f));
      }
      float mx = fmaxf(fmaxf(lg[0], lg[1]), fmaxf(lg[2], lg[3]));
#pragma unroll
      for (int off = 8; off; off >>= 1) mx = fmaxf(mx, __shfl_xor(mx, off, 16));
      float sum = 0.f;
#pragma unroll
      for (int u = 0; u < 4; ++u) { float e = exp2f((lg[u] - mx) * LOG2E); lg[u] = e; sum += e; }
#pragma unroll
      for (int off = 8; off; off >>= 1) sum += __shfl_xor(sum, off, 16);
      float rs = 1.f / sum;
#pragma unroll
      for (int u = 0; u < 4; ++u) {
        int col = aci + u * 16;
        float av = lg[u] * rs;
        aT[(size_t)col * 4096 + rbase + arow] = (bf16)av;
        atomicAdd(&asl[col], av);
      }
      __syncthreads();
      if (tid < 64) atomicAdd(&asumall[par * 64 + tid], asl[tid]);
    }
    gridbar(bar, ep, g);
    // ================= phase B =================
    if (b < 192) {
      const bf16* Ar = aT + (size_t)(tr * 16 + c) * 4096 + q2 * 8;
      f32x4 b0 = {}, b1 = {}, b2 = {}, b3 = {};
#pragma unroll
      for (int i = 0; i < 32; i += 4) {
#pragma unroll
        for (int u = 0; u < 4; ++u) {
          int ii = i + u;
          int kb = (w + ii * 4) * 32;
          int gb = (w + ii * 4) * 4 + q2;
          bf16x8 bv = *(const bf16x8*)&XtL[(size_t)c * 4096 + ((gb ^ (c & 7)) * 8)];
          bf16x8 av = *(const bf16x8*)(Ar + kb);
          if (u == 0) b0 = mfma16(av, bv, b0);
          else if (u == 1) b1 = mfma16(av, bv, b1);
          else if (u == 2) b2 = mfma16(av, bv, b2);
          else b3 = mfma16(av, bv, b3);
        }
      }
      f32x4 acc = (b0 + b1) + (b2 + b3);
#pragma unroll
      for (int j = 0; j < 4; ++j) red[w][q2 * 4 + j][c] = acc[j];
      if (tid < 16) cnl[tid] = 0.f;
      __syncthreads();
      const int r = tid >> 4, cl = tid & 15;
      float s = red[0][r][cl] + red[1][r][cl] + red[2][r][cl] + red[3][r][cl];
      const int cluster = tr * 16 + r, dcol = tc * 16 + cl;
      float denom = asumall[par * 64 + cluster] + 1e-6f;
      float cnew = s / denom;
      size_t cidx = (size_t)cluster * 768 + dcol;
      float cold = CB[(size_t)par * 49152 + cidx];
      CB[(size_t)(par ^ 1) * 49152 + cidx] = cnew;
      CBH[(size_t)(par ^ 1) * 49152 + cidx] = (bf16)cnew;
      atomicAdd(&cnl[r], cnew * cnew);
      float dv = fabsf(cnew - cold);
#pragma unroll
      for (int off = 32; off; off >>= 1) dv += __shfl_xor(dv, off, 64);
      if (lane == 0) dred[w] = dv;
      __syncthreads();
      if (tid < 16)
        atomicAdd(&cnall[(par ^ 1) * 64 + tr * 16 + tid], cnl[tid]);
      if (tid == 0)
        atomicAdd(&diffall[par], dred[0] + dred[1] + dred[2] + dred[3]);
    } else if (b == 255 && tid == 0) {
      diffall[par ^ 1] = 0.f;
    }
    gridbar(bar, ep, g);
    if (tid == 0)
      sdiff = *(volatile const float*)&diffall[par];
    __syncthreads();
    if (sdiff <= 1e-4f) { p = par; break; }
    p = (t + 1) & 1;
  }
  // ================= final: a_p from C_p; copy C_p out =================
  {
    const bf16* C = CBH + (size_t)p * 49152;
    const float* cnp = cnall + p * 64;
    f32x4 acc = {};
    const bf16* Cr = C + (size_t)(w * 16 + c) * 768 + q2 * 8;
#pragma unroll
    for (int ks = 0; ks < 24; ++ks) {
      bf16x8 a = *(const bf16x8*)&XL[c][q2 * 8 + ks * 32];
      bf16x8 bb = *(const bf16x8*)(Cr + ks * 32);
      acc = mfma16(a, bb, acc);
    }
    __syncthreads();
#pragma unroll
    for (int j = 0; j < 4; ++j) Gs[q2 * 4 + j][w * 16 + c] = acc[j];
    __syncthreads();
    float lg[4];
#pragma unroll
    for (int u = 0; u < 4; ++u) {
      int col = aci + u * 16;
      float d2 = xn + cnp[col] - 2.f * Gs[arow][col];
      lg[u] = -2.f * sqrtf(fmaxf(d2, 0.f));
    }
    float mx = fmaxf(fmaxf(lg[0], lg[1]), fmaxf(lg[2], lg[3]));
#pragma unroll
    for (int off = 8; off; off >>= 1) mx = fmaxf(mx, __shfl_xor(mx, off, 16));
    float sum = 0.f;
#pragma unroll
    for (int u = 0; u < 4; ++u) { float e = exp2f((lg[u] - mx) * LOG2E); lg[u] = e; sum += e; }
#pragma unroll
    for (int off = 8; off; off >>= 1) sum += __shfl_xor(sum, off, 16);
    float rs = 1.f / sum;
#pragma unroll
    for (int u = 0; u < 4; ++u)
      a_out[(size_t)(rbase + arow) * 64 + aci + u * 16] = lg[u] * rs;
  }
  if (tid < 192) outC[b * 192 + tid] = CB[(size_t)p * 49152 + b * 192 + tid];
}

extern "C" void kernel_launch(void* const* d_in, const int* in_sizes, int n_in,
                              void* d_out, int out_size, void* d_ws, size_t ws_size,
                              hipStream_t stream) {
  const float* x0   = (const float*)d_in[0];
  const float* fc1w = (const float*)d_in[1];
  const float* fc1b = (const float*)d_in[2];
  const float* fc2w = (const float*)d_in[3];
  const float* fc2b = (const float*)d_in[4];
  const float* ipw  = (const float*)d_in[5];
  const float* ipb  = (const float*)d_in[6];
  const float* outw = (const float*)d_in[7];
  const float* outbias = (const float*)d_in[8];
  const float* lng  = (const float*)d_in[9];
  const float* lnb  = (const float*)d_in[10];
  const int*   idx  = (const int*)d_in[11];

  char* p = (char*)d_ws;
  auto take = [&](size_t n) { char* r = p; p += (n + 255) & ~(size_t)255; return r; };
  bf16* X0B   = (bf16*)take((size_t)4096 * 768 * 2);
  bf16* W1B   = (bf16*)take((size_t)768 * 768 * 2);
  bf16* FC2WB = (bf16*)take((size_t)768 * 768 * 2);
  bf16* IPWB  = (bf16*)take((size_t)2304 * 768 * 2);
  bf16* OUTWB = (bf16*)take((size_t)768 * 768 * 2);
  bf16* HB    = (bf16*)take((size_t)4096 * 768 * 2);
  bf16* QKVB  = (bf16*)take((size_t)4096 * 2304 * 2);
  bf16* VT    = (bf16*)take((size_t)768 * 4096 * 2);
  bf16* OB    = (bf16*)take((size_t)4096 * 768 * 2);
  bf16* O2B   = (bf16*)take((size_t)4096 * 768 * 2);
  float* YF   = (float*)take((size_t)4096 * 768 * 4);
  float* XF   = (float*)take((size_t)4096 * 768 * 4);
  bf16* XBB   = (bf16*)take((size_t)4096 * 768 * 2);
  bf16* XTB   = (bf16*)take((size_t)768 * 4096 * 2);
  float* XN2  = (float*)take((size_t)4096 * 4);
  float* CB   = (float*)take((size_t)2 * 49152 * 4);
  bf16* CBH   = (bf16*)take((size_t)2 * 49152 * 2);
  bf16* ATB   = (bf16*)take((size_t)64 * 4096 * 2);
  float* CTRLF = (float*)take(8192 * 4);
  float* ASUM = CTRLF;
  float* CN   = CTRLF + 128;
  float* DIFF = CTRLF + 256;
  int* BAR    = (int*)(CTRLF + 512);

  float* aout = (float*)d_out + 49152;

  cvt_all<<<6528, 256, 0, stream>>>(x0, fc1w, fc2w, ipw, outw,
                                    X0B, W1B, FC2WB, IPWB, OUTWB, CTRLF);
  gemm128<1, 0><<<dim3(32, 6), 256, 0, stream>>>(X0B, W1B, fc1b, HB, nullptr, 768);
  gemm128<0, 0><<<dim3(32, 18), 256, 0, stream>>>(HB, IPWB, ipb, QKVB, nullptr, 2304);
  transpose_bf16<<<dim3(64, 12), 256, 0, stream>>>(QKVB, VT, 2304, 1536, 4096);
  attn_kernel<<<768, 256, 0, stream>>>(QKVB, VT, OB);
  gemm128<0, 0><<<dim3(32, 6), 256, 0, stream>>>(OB, OUTWB, outbias, O2B, nullptr, 768);
  gemm128<1, 1><<<dim3(32, 6), 256, 0, stream>>>(O2B, FC2WB, fc2b, nullptr, YF, 768);
  ln_kernel<<<1024, 256, 0, stream>>>(x0, YF, lng, lnb, XF, XBB, XN2);
  transpose_bf16<<<dim3(64, 12), 256, 0, stream>>>(XBB, XTB, 768, 0, 4096);
  dkm_fused<<<256, 256, 131072, stream>>>(XF, idx, XBB, XTB, XN2, CB, CBH, ATB, aout,
                                          (float*)d_out, ASUM, CN, DIFF, BAR);
}

// Round 12
// 539.545 us; speedup vs baseline: 1.2654x; 1.0034x over previous
//
#include <hip/hip_runtime.h>
#include <cstdint>

typedef __bf16 bf16;
typedef __bf16 bf16x4 __attribute__((ext_vector_type(4)));
typedef __bf16 bf16x8 __attribute__((ext_vector_type(8)));
typedef float  f32x4  __attribute__((ext_vector_type(4)));

#define LOG2E 1.44269504088896340736f

__device__ __forceinline__ f32x4 mfma16(bf16x8 a, bf16x8 b, f32x4 c) {
  return __builtin_amdgcn_mfma_f32_16x16x32_bf16(a, b, c, 0, 0, 0);
}

// async global->LDS, 16B per lane; LDS dest must be wave-uniform base + lane*16
__device__ __forceinline__ void gl2lds16(const bf16* g, bf16* l) {
  __builtin_amdgcn_global_load_lds(
      (const __attribute__((address_space(1))) unsigned int*)g,
      (__attribute__((address_space(3))) unsigned int*)l, 16, 0, 0);
}

__device__ __forceinline__ int pack_bf16x2(float lo, float hi) {
  union { bf16 h[2]; int i; } u;
  u.h[0] = (bf16)lo; u.h[1] = (bf16)hi;
  return u.i;
}

// ---------------- convert f32 -> bf16 + zero DKM control area (32 KB) ----------------
__global__ __launch_bounds__(256) void cvt_all(
    const float* __restrict__ x0, const float* __restrict__ w1,
    const float* __restrict__ w2, const float* __restrict__ wip,
    const float* __restrict__ wo,
    bf16* __restrict__ dx0, bf16* __restrict__ dw1, bf16* __restrict__ dw2,
    bf16* __restrict__ dwip, bf16* __restrict__ dwo, float* __restrict__ ctrl)
{
  int i = blockIdx.x * 256 + threadIdx.x;
  if (blockIdx.x == 0) {
    for (int u = threadIdx.x; u < 8192; u += 256) ctrl[u] = 0.f;
  }
  const float* s; bf16* d; int base;
  if      (i <  786432) { s = x0;  d = dx0;  base = 0; }
  else if (i <  933888) { s = w1;  d = dw1;  base = 786432; }
  else if (i < 1081344) { s = w2;  d = dw2;  base = 933888; }
  else if (i < 1523712) { s = wip; d = dwip; base = 1081344; }
  else                  { s = wo;  d = dwo;  base = 1523712; }
  int j = i - base;
  f32x4 v = ((const f32x4*)s)[j];
  bf16x4 r;
  r[0] = (bf16)v[0]; r[1] = (bf16)v[1]; r[2] = (bf16)v[2]; r[3] = (bf16)v[3];
  ((bf16x4*)d)[j] = r;
}

// ---------------- 128x128-tile GEMM: out = act(A[M,768] @ W[N,768]^T + bias) ----------------
// WRITEVT: also write transposed copy of cols >=1536 to vtout[col-1536][row] (V of QKV)
template<int RELU, int OUTF32, int WRITEVT>
__global__ __launch_bounds__(256) void gemm128(
    const bf16* __restrict__ A, const bf16* __restrict__ W,
    const float* __restrict__ bias, bf16* __restrict__ outb,
    float* __restrict__ outf, int N, bf16* __restrict__ vtout)
{
  __shared__ bf16 Ab[2][8192];   // [128][64]
  __shared__ bf16 Bb[2][8192];
  const int tid = threadIdx.x;
  const int w = tid >> 6, lane = tid & 63;
  const int q2 = lane >> 4, c = lane & 15;
  const int wrow = (w >> 1) * 64, wcol = (w & 1) * 64;
  const int mb = blockIdx.x * 128, nb = blockIdx.y * 128;
  const int srow = tid >> 3, sgrp = tid & 7;

  auto stage = [&](const bf16* __restrict__ src, int rowbase, int kb, bf16* dst) {
#pragma unroll
    for (int i = 0; i < 4; ++i) {
      int row = i * 32 + srow;
      int gs = (sgrp ^ (row & 7)) * 8;
      gl2lds16(src + (size_t)(rowbase + row) * 768 + kb + gs,
               dst + i * 2048 + tid * 8);
    }
  };

  f32x4 acc[4][4] = {};
  stage(A, mb, 0, Ab[0]);
  stage(W, nb, 0, Bb[0]);
  for (int kb = 0; kb < 12; ++kb) {
    const int buf = kb & 1;
    __syncthreads();
    if (kb < 11) {
      stage(A, mb, (kb + 1) * 64, Ab[buf ^ 1]);
      stage(W, nb, (kb + 1) * 64, Bb[buf ^ 1]);
    }
#pragma unroll
    for (int kc = 0; kc < 2; ++kc) {
      bf16x8 af[4], bfr[4];
#pragma unroll
      for (int rt = 0; rt < 4; ++rt) {
        int r = wrow + rt * 16 + c;
        af[rt] = *(const bf16x8*)&Ab[buf][r * 64 + (((kc * 4 + q2) ^ (r & 7)) * 8)];
      }
#pragma unroll
      for (int ct = 0; ct < 4; ++ct) {
        int r = wcol + ct * 16 + c;
        bfr[ct] = *(const bf16x8*)&Bb[buf][r * 64 + (((kc * 4 + q2) ^ (r & 7)) * 8)];
      }
#pragma unroll
      for (int rt = 0; rt < 4; ++rt)
#pragma unroll
        for (int ct = 0; ct < 4; ++ct)
          acc[rt][ct] = mfma16(af[rt], bfr[ct], acc[rt][ct]);
    }
  }
#pragma unroll
  for (int rt = 0; rt < 4; ++rt) {
#pragma unroll
    for (int ct = 0; ct < 4; ++ct) {
      int col = nb + wcol + ct * 16 + c;
      float bv = bias[col];
      bf16x4 vv;
#pragma unroll
      for (int j = 0; j < 4; ++j) {
        int row = mb + wrow + rt * 16 + q2 * 4 + j;
        float v = acc[rt][ct][j] + bv;
        if (RELU) v = fmaxf(v, 0.f);
        if (OUTF32) outf[(size_t)row * N + col] = v;
        else { outb[(size_t)row * N + col] = (bf16)v; vv[j] = (bf16)v; }
      }
      if (WRITEVT && col >= 1536) {
        int row0 = mb + wrow + rt * 16 + q2 * 4;
        *(bf16x4*)&vtout[(size_t)(col - 1536) * 4096 + row0] = vv;
      }
    }
  }
}

// ---------------- 64x64 tile transpose ----------------
__global__ __launch_bounds__(256) void transpose_bf16(
    const bf16* __restrict__ src, bf16* __restrict__ dst,
    int stride, int colOff, int dstride)
{
  __shared__ bf16 t[64][72];
  const int br = blockIdx.x, bc = blockIdx.y;
  {
    int ir = threadIdx.x >> 2, icb = (threadIdx.x & 3) * 16;
    const bf16* srow = src + (size_t)(br * 64 + ir) * stride + colOff + bc * 64 + icb;
    *(bf16x8*)&t[ir][icb] = *(const bf16x8*)srow;
    *(bf16x8*)&t[ir][icb + 8] = *(const bf16x8*)(srow + 8);
  }
  __syncthreads();
  {
    int oc = threadIdx.x >> 2, orb = (threadIdx.x & 3) * 16;
    bf16x8 v0, v1;
#pragma unroll
    for (int j = 0; j < 8; ++j) { v0[j] = t[orb + j][oc]; v1[j] = t[orb + 8 + j][oc]; }
    bf16* drow = dst + (size_t)(bc * 64 + oc) * dstride + br * 64 + orb;
    *(bf16x8*)drow = v0;
    *(bf16x8*)(drow + 8) = v1;
  }
}

// ---------------- flash attention v3: transposed scores, no Pl (32 KB LDS) ----------------
// S^T = K Q^T (A=K, B=Q); P^T -> PV B-frags via in-wave ds_bpermute; O^T = V^T P^T.
__global__ __launch_bounds__(256) void attn_kernel(
    const bf16* __restrict__ qkv, const bf16* __restrict__ vt, bf16* __restrict__ o)
{
  const int h = blockIdx.x >> 6;
  const int qt = blockIdx.x & 63;
  const int w = threadIdx.x >> 6, lane = threadIdx.x & 63;
  const int q2 = lane >> 4, c = lane & 15;
  const int qbase = qt * 64 + w * 16;
  __shared__ bf16 Ks[2][64][64];
  __shared__ bf16 Vs[2][64][64];

  // Q B-frags: B[n=c][k=d]
  const bf16* Qr = qkv + (size_t)(qbase + c) * 2304 + h * 64 + q2 * 8;
  bf16x8 a0 = *(const bf16x8*)(Qr);
  bf16x8 a1 = *(const bf16x8*)(Qr + 32);

  const int srow = lane >> 3;
  const int sg = ((lane & 7) ^ srow) * 8;
  const bf16* kg = qkv + (size_t)(w * 16 + srow) * 2304 + 768 + h * 64 + sg;
  const bf16* vg = vt + (size_t)(h * 64 + w * 16 + srow) * 4096 + sg;

  auto stage = [&](int jt, int buf) {
    const int kvb = jt * 64;
    gl2lds16(kg + (size_t)kvb * 2304,       &Ks[buf][w * 16][0]);
    gl2lds16(kg + (size_t)(kvb + 8) * 2304, &Ks[buf][w * 16 + 8][0]);
    gl2lds16(vg + kvb,                      &Vs[buf][w * 16][0]);
    gl2lds16(vg + kvb + 8 * 4096,           &Vs[buf][w * 16 + 8][0]);
  };

  bf16x8 ones;
#pragma unroll
  for (int i = 0; i < 8; ++i) ones[i] = (bf16)1.0f;

  f32x4 oa[4] = {};
  f32x4 accl = {};
  const int gsw = (q2 ^ (c & 7)) * 8;
  const float SC = 0.125f * LOG2E;
  // bpermute source lanes (byte index = lane*4); sources are within this wave
  const int L0 = ((q2 & 1) * 2 * 16 + c) * 4;
  const int L1 = (((q2 & 1) * 2 + 1) * 16 + c) * 4;
  const bool hi = (q2 & 2) != 0;

  stage(0, 0);
  for (int jt = 0; jt < 64; ++jt) {
    const int buf = jt & 1;
    __syncthreads();
    if (jt < 63) stage(jt + 1, buf ^ 1);
    // ---- S^T[kv][q]: 4 blocks of 16 kv; thread holds S[kv=nt*16+q2*4+j][q=c] ----
    f32x4 st[4];
#pragma unroll
    for (int nt = 0; nt < 4; ++nt) {
      const int row = nt * 16 + c;
      bf16x8 k0 = *(const bf16x8*)&Ks[buf][row][gsw];
      bf16x8 k1 = *(const bf16x8*)&Ks[buf][row][gsw ^ 32];
      f32x4 t = {};
      t = mfma16(k0, a0, t);
      t = mfma16(k1, a1, t);
      st[nt] = t;
    }
    // ---- P^T = exp(S^T/8), packed bf16x2 per (nt, j-pair) ----
    int pk[4][2];
#pragma unroll
    for (int nt = 0; nt < 4; ++nt) {
      pk[nt][0] = pack_bf16x2(exp2f(st[nt][0] * SC), exp2f(st[nt][1] * SC));
      pk[nt][1] = pack_bf16x2(exp2f(st[nt][2] * SC), exp2f(st[nt][3] * SC));
    }
    // ---- gather PV B-frags: p0 = P[q=c][kv=q2*8+jj], p1 = +32 (in-wave transpose) ----
    int r_lo[2][4], r_hi[2][4];   // [src L][nt-pairs] -> select by hi (q2>>1)
#pragma unroll
    for (int hh = 0; hh < 2; ++hh) {
      r_lo[0][hh]     = __builtin_amdgcn_ds_bpermute(L0, pk[0][hh]);
      r_hi[0][hh]     = __builtin_amdgcn_ds_bpermute(L0, pk[1][hh]);
      r_lo[1][hh]     = __builtin_amdgcn_ds_bpermute(L1, pk[0][hh]);
      r_hi[1][hh]     = __builtin_amdgcn_ds_bpermute(L1, pk[1][hh]);
      r_lo[0][2 + hh] = __builtin_amdgcn_ds_bpermute(L0, pk[2][hh]);
      r_hi[0][2 + hh] = __builtin_amdgcn_ds_bpermute(L0, pk[3][hh]);
      r_lo[1][2 + hh] = __builtin_amdgcn_ds_bpermute(L1, pk[2][hh]);
      r_hi[1][2 + hh] = __builtin_amdgcn_ds_bpermute(L1, pk[3][hh]);
    }
    union { int i[4]; bf16x8 v; } u0, u1;
    u0.i[0] = hi ? r_hi[0][0] : r_lo[0][0];
    u0.i[1] = hi ? r_hi[0][1] : r_lo[0][1];
    u0.i[2] = hi ? r_hi[1][0] : r_lo[1][0];
    u0.i[3] = hi ? r_hi[1][1] : r_lo[1][1];
    u1.i[0] = hi ? r_hi[0][2] : r_lo[0][2];
    u1.i[1] = hi ? r_hi[0][3] : r_lo[0][3];
    u1.i[2] = hi ? r_hi[1][2] : r_lo[1][2];
    u1.i[3] = hi ? r_hi[1][3] : r_lo[1][3];
    bf16x8 p0 = u0.v, p1 = u1.v;
    // ---- row sums: ones as A -> every D row = sum_kv P[q=c][kv] ----
    accl = mfma16(ones, p0, accl);
    accl = mfma16(ones, p1, accl);
    // ---- O^T += V^T P^T: A = V^T (Vs rows), B = p0/p1 ----
#pragma unroll
    for (int dt = 0; dt < 4; ++dt) {
      const int row = dt * 16 + c;
      bf16x8 v0 = *(const bf16x8*)&Vs[buf][row][gsw];
      bf16x8 v1 = *(const bf16x8*)&Vs[buf][row][gsw ^ 32];
      oa[dt] = mfma16(v0, p0, oa[dt]);
      oa[dt] = mfma16(v1, p1, oa[dt]);
    }
  }
  // ---- O^T: row = d = dt*16+q2*4+j, col = q = c; write o[q][h*64+d] packed x4 ----
  const float inv = 1.f / accl[0];
#pragma unroll
  for (int dt = 0; dt < 4; ++dt) {
    bf16x4 ov;
#pragma unroll
    for (int j = 0; j < 4; ++j) ov[j] = (bf16)(oa[dt][j] * inv);
    *(bf16x4*)&o[(size_t)(qbase + c) * 768 + h * 64 + dt * 16 + q2 * 4] = ov;
  }
}

// ---------------- residual + layernorm (bf16 X out only) ----------------
__global__ __launch_bounds__(256) void ln_kernel(
    const float* __restrict__ x0, const float* __restrict__ y,
    const float* __restrict__ g, const float* __restrict__ b,
    bf16* __restrict__ Xb, float* __restrict__ xn2)
{
  const int w = threadIdx.x >> 6, lane = threadIdx.x & 63;
  const int row = blockIdx.x * 4 + w;
  const float* xr = x0 + (size_t)row * 768;
  const float* yr = y + (size_t)row * 768;
  float z[12]; float s = 0.f;
#pragma unroll
  for (int i = 0; i < 12; ++i) {
    int col = lane + i * 64;
    float zz = 0.5f * xr[col] + 0.5f * yr[col];
    z[i] = zz; s += zz;
  }
#pragma unroll
  for (int off = 32; off; off >>= 1) s += __shfl_xor(s, off, 64);
  float mu = s * (1.f / 768.f);
  float v = 0.f;
#pragma unroll
  for (int i = 0; i < 12; ++i) { float d = z[i] - mu; v += d * d; }
#pragma unroll
  for (int off = 32; off; off >>= 1) v += __shfl_xor(v, off, 64);
  float rstd = rsqrtf(v * (1.f / 768.f) + 1e-5f);
  float sn = 0.f;
#pragma unroll
  for (int i = 0; i < 12; ++i) {
    int col = lane + i * 64;
    float xv = (z[i] - mu) * rstd * g[col] + b[col];
    Xb[(size_t)row * 768 + col] = (bf16)xv;
    sn += xv * xv;
  }
#pragma unroll
  for (int off = 32; off; off >>= 1) sn += __shfl_xor(sn, off, 64);
  if (lane == 0) xn2[row] = sn;
}

// ---------------- grid barrier: monotone counters, split fences (256 blocks) ----------------
__device__ __forceinline__ void gridbar(int* bar, int& ep, int g) {
  __syncthreads();
  if (threadIdx.x == 0) {
    ep++;
    __builtin_amdgcn_fence(__ATOMIC_RELEASE, "agent");
    int v = __hip_atomic_fetch_add(bar + g * 64, 1, __ATOMIC_RELAXED,
                                   __HIP_MEMORY_SCOPE_AGENT) + 1;
    if (v == 32 * ep) {
      int tv = __hip_atomic_fetch_add(bar + 512, 1, __ATOMIC_RELAXED,
                                      __HIP_MEMORY_SCOPE_AGENT) + 1;
      if (tv == 8 * ep) {
#pragma unroll
        for (int i = 0; i < 8; ++i)
          __hip_atomic_store(bar + 1024 + i * 64, ep, __ATOMIC_RELAXED,
                             __HIP_MEMORY_SCOPE_AGENT);
      }
    }
    long guard = 0;
    while (__hip_atomic_load(bar + 1024 + g * 64, __ATOMIC_RELAXED,
                             __HIP_MEMORY_SCOPE_AGENT) < ep) {
      __builtin_amdgcn_s_sleep(2);
      if (++guard > (1L << 28)) break;
    }
    __builtin_amdgcn_fence(__ATOMIC_ACQUIRE, "agent");
  }
  __syncthreads();
}

// ---------------- fused DKM (R9 structure): grid 256 x 256, dynLDS 128 KB ----------------
__global__ __launch_bounds__(256) void dkm_fused(
    const int* __restrict__ idx,
    const bf16* __restrict__ Xb, const bf16* __restrict__ Xt,
    const float* __restrict__ xn2,
    float* __restrict__ CB, bf16* __restrict__ CBH,
    bf16* __restrict__ aT, float* __restrict__ a_out, float* __restrict__ outC,
    float* __restrict__ asumall, float* __restrict__ cnall,
    float* __restrict__ diffall, int* __restrict__ bar)
{
  extern __shared__ char dynsmem[];
  bf16* XtL = (bf16*)dynsmem;
  __shared__ bf16 XL[16][776];
  __shared__ float GsRed[1024];
  __shared__ float asl[64];
  __shared__ float cnl[16];
  __shared__ float dred[4];
  __shared__ float sdiff;
  float (*Gs)[64] = (float(*)[64])GsRed;
  float (*red)[16][16] = (float(*)[16][16])GsRed;
  const int tid = threadIdx.x;
  const int w = tid >> 6, lane = tid & 63;
  const int q2 = lane >> 4, c = lane & 15;
  const int b = blockIdx.x;
  const int g = b & 7;
  const int rbase = b * 16;
  const int tr = b / 48, tc = b % 48;
  int ep = 0;

  {
    int row = tid >> 4, seg = (tid & 15) * 48;
    const bf16* src = Xb + (size_t)(rbase + row) * 768 + seg;
#pragma unroll
    for (int i = 0; i < 6; ++i)
      *(bf16x8*)&XL[row][seg + i * 8] = *(const bf16x8*)(src + i * 8);
  }
  if (b < 192) {
    const int row = tid >> 4, cc = tid & 15;
    const bf16* XtS = Xt + (size_t)(tc * 16 + row) * 4096;
#pragma unroll
    for (int i = 0; i < 32; ++i) {
      int gg = i * 16 + cc;
      bf16x8 vv = *(const bf16x8*)(XtS + gg * 8);
      *(bf16x8*)&XtL[(size_t)row * 4096 + ((gg ^ (row & 7)) * 8)] = vv;
    }
  }
  if (b < 64) {
    const int src = idx[b];
    float s = 0.f;
#pragma unroll
    for (int u = 0; u < 3; ++u) {
      int d = u * 256 + tid;
      bf16 xv = Xb[(size_t)src * 768 + d];
      float v = (float)xv;
      CB[(size_t)b * 768 + d] = v;
      CBH[(size_t)b * 768 + d] = xv;
      s += v * v;
    }
#pragma unroll
    for (int off = 32; off; off >>= 1) s += __shfl_xor(s, off, 64);
    if (lane == 0) dred[w] = s;
    __syncthreads();
    if (tid == 0) cnall[b] = dred[0] + dred[1] + dred[2] + dred[3];
  }
  const int arow = tid >> 4, aci = tid & 15;
  const float xn = xn2[rbase + arow];
  gridbar(bar, ep, g);

  int p = 0;
  for (int t = 0; t < 100; ++t) {
    const int par = t & 1;
    // ================= phase A =================
    {
      if (b == 0) {
        if (tid >= 128 && tid < 192) asumall[(par ^ 1) * 64 + tid - 128] = 0.f;
        else if (tid >= 192)         cnall[(par ^ 1) * 64 + tid - 192] = 0.f;
      }
      const bf16* C = CBH + (size_t)par * 49152;
      const float* cnp = cnall + par * 64;
      const bf16* Cr = C + (size_t)(w * 16 + c) * 768 + q2 * 8;
      f32x4 a0 = {}, a1 = {}, a2 = {}, a3 = {};
#pragma unroll
      for (int ks = 0; ks < 24; ks += 4) {
        a0 = mfma16(*(const bf16x8*)&XL[c][q2 * 8 + ks * 32],
                    *(const bf16x8*)(Cr + ks * 32), a0);
        a1 = mfma16(*(const bf16x8*)&XL[c][q2 * 8 + (ks + 1) * 32],
                    *(const bf16x8*)(Cr + (ks + 1) * 32), a1);
        a2 = mfma16(*(const bf16x8*)&XL[c][q2 * 8 + (ks + 2) * 32],
                    *(const bf16x8*)(Cr + (ks + 2) * 32), a2);
        a3 = mfma16(*(const bf16x8*)&XL[c][q2 * 8 + (ks + 3) * 32],
                    *(const bf16x8*)(Cr + (ks + 3) * 32), a3);
      }
      f32x4 acc = (a0 + a1) + (a2 + a3);
      if (tid < 64) asl[tid] = 0.f;
#pragma unroll
      for (int j = 0; j < 4; ++j) Gs[q2 * 4 + j][w * 16 + c] = acc[j];
      __syncthreads();
      float lg[4];
#pragma unroll
      for (int u = 0; u < 4; ++u) {
        int col = aci + u * 16;
        float d2 = xn + cnp[col] - 2.f * Gs[arow][col];
        lg[u] = -2.f * sqrtf(fmaxf(d2, 0.f));
      }
      float mx = fmaxf(fmaxf(lg[0], lg[1]), fmaxf(lg[2], lg[3]));
#pragma unroll
      for (int off = 8; off; off >>= 1) mx = fmaxf(mx, __shfl_xor(mx, off, 16));
      float sum = 0.f;
#pragma unroll
      for (int u = 0; u < 4; ++u) { float e = exp2f((lg[u] - mx) * LOG2E); lg[u] = e; sum += e; }
#pragma unroll
      for (int off = 8; off; off >>= 1) sum += __shfl_xor(sum, off, 16);
      float rs = 1.f / sum;
#pragma unroll
      for (int u = 0; u < 4; ++u) {
        int col = aci + u * 16;
        float av = lg[u] * rs;
        aT[(size_t)col * 4096 + rbase + arow] = (bf16)av;
        atomicAdd(&asl[col], av);
      }
      __syncthreads();
      if (tid < 64) atomicAdd(&asumall[par * 64 + tid], asl[tid]);
    }
    gridbar(bar, ep, g);
    // ================= phase B =================
    if (b < 192) {
      const bf16* Ar = aT + (size_t)(tr * 16 + c) * 4096 + q2 * 8;
      f32x4 b0 = {}, b1 = {}, b2 = {}, b3 = {};
#pragma unroll
      for (int i = 0; i < 32; i += 4) {
#pragma unroll
        for (int u = 0; u < 4; ++u) {
          int ii = i + u;
          int kb = (w + ii * 4) * 32;
          int gb = (w + ii * 4) * 4 + q2;
          bf16x8 bv = *(const bf16x8*)&XtL[(size_t)c * 4096 + ((gb ^ (c & 7)) * 8)];
          bf16x8 av = *(const bf16x8*)(Ar + kb);
          if (u == 0) b0 = mfma16(av, bv, b0);
          else if (u == 1) b1 = mfma16(av, bv, b1);
          else if (u == 2) b2 = mfma16(av, bv, b2);
          else b3 = mfma16(av, bv, b3);
        }
      }
      f32x4 acc = (b0 + b1) + (b2 + b3);
#pragma unroll
      for (int j = 0; j < 4; ++j) red[w][q2 * 4 + j][c] = acc[j];
      if (tid < 16) cnl[tid] = 0.f;
      __syncthreads();
      const int r = tid >> 4, cl = tid & 15;
      float s = red[0][r][cl] + red[1][r][cl] + red[2][r][cl] + red[3][r][cl];
      const int cluster = tr * 16 + r, dcol = tc * 16 + cl;
      float denom = asumall[par * 64 + cluster] + 1e-6f;
      float cnew = s / denom;
      size_t cidx = (size_t)cluster * 768 + dcol;
      float cold = CB[(size_t)par * 49152 + cidx];
      CB[(size_t)(par ^ 1) * 49152 + cidx] = cnew;
      CBH[(size_t)(par ^ 1) * 49152 + cidx] = (bf16)cnew;
      atomicAdd(&cnl[r], cnew * cnew);
      float dv = fabsf(cnew - cold);
#pragma unroll
      for (int off = 32; off; off >>= 1) dv += __shfl_xor(dv, off, 64);
      if (lane == 0) dred[w] = dv;
      __syncthreads();
      if (tid < 16)
        atomicAdd(&cnall[(par ^ 1) * 64 + tr * 16 + tid], cnl[tid]);
      if (tid == 0)
        atomicAdd(&diffall[par], dred[0] + dred[1] + dred[2] + dred[3]);
    } else if (b == 255 && tid == 0) {
      diffall[par ^ 1] = 0.f;
    }
    gridbar(bar, ep, g);
    if (tid == 0)
      sdiff = *(volatile const float*)&diffall[par];
    __syncthreads();
    if (sdiff <= 1e-4f) { p = par; break; }
    p = (t + 1) & 1;
  }
  // ================= final: a_p from C_p; copy C_p out =================
  {
    const bf16* C = CBH + (size_t)p * 49152;
    const float* cnp = cnall + p * 64;
    f32x4 acc = {};
    const bf16* Cr = C + (size_t)(w * 16 + c) * 768 + q2 * 8;
#pragma unroll
    for (int ks = 0; ks < 24; ++ks) {
      bf16x8 a = *(const bf16x8*)&XL[c][q2 * 8 + ks * 32];
      bf16x8 bb = *(const bf16x8*)(Cr + ks * 32);
      acc = mfma16(a, bb, acc);
    }
    __syncthreads();
#pragma unroll
    for (int j = 0; j < 4; ++j) Gs[q2 * 4 + j][w * 16 + c] = acc[j];
    __syncthreads();
    float lg[4];
#pragma unroll
    for (int u = 0; u < 4; ++u) {
      int col = aci + u * 16;
      float d2 = xn + cnp[col] - 2.f * Gs[arow][col];
      lg[u] = -2.f * sqrtf(fmaxf(d2, 0.f));
    }
    float mx = fmaxf(fmaxf(lg[0], lg[1]), fmaxf(lg[2], lg[3]));
#pragma unroll
    for (int off = 8; off; off >>= 1) mx = fmaxf(mx, __shfl_xor(mx, off, 16));
    float sum = 0.f;
#pragma unroll
    for (int u = 0; u < 4; ++u) { float e = exp2f((lg[u] - mx) * LOG2E); lg[u] = e; sum += e; }
#pragma unroll
    for (int off = 8; off; off >>= 1) sum += __shfl_xor(sum, off, 16);
    float rs = 1.f / sum;
#pragma unroll
    for (int u = 0; u < 4; ++u)
      a_out[(size_t)(rbase + arow) * 64 + aci + u * 16] = lg[u] * rs;
  }
  if (tid < 192) outC[b * 192 + tid] = CB[(size_t)p * 49152 + b * 192 + tid];
}

extern "C" void kernel_launch(void* const* d_in, const int* in_sizes, int n_in,
                              void* d_out, int out_size, void* d_ws, size_t ws_size,
                              hipStream_t stream) {
  const float* x0   = (const float*)d_in[0];
  const float* fc1w = (const float*)d_in[1];
  const float* fc1b = (const float*)d_in[2];
  const float* fc2w = (const float*)d_in[3];
  const float* fc2b = (const float*)d_in[4];
  const float* ipw  = (const float*)d_in[5];
  const float* ipb  = (const float*)d_in[6];
  const float* outw = (const float*)d_in[7];
  const float* outbias = (const float*)d_in[8];
  const float* lng  = (const float*)d_in[9];
  const float* lnb  = (const float*)d_in[10];
  const int*   idx  = (const int*)d_in[11];

  char* p = (char*)d_ws;
  auto take = [&](size_t n) { char* r = p; p += (n + 255) & ~(size_t)255; return r; };
  bf16* X0B   = (bf16*)take((size_t)4096 * 768 * 2);
  bf16* W1B   = (bf16*)take((size_t)768 * 768 * 2);
  bf16* FC2WB = (bf16*)take((size_t)768 * 768 * 2);
  bf16* IPWB  = (bf16*)take((size_t)2304 * 768 * 2);
  bf16* OUTWB = (bf16*)take((size_t)768 * 768 * 2);
  bf16* HB    = (bf16*)take((size_t)4096 * 768 * 2);
  bf16* QKVB  = (bf16*)take((size_t)4096 * 2304 * 2);
  bf16* VT    = (bf16*)take((size_t)768 * 4096 * 2);
  bf16* OB    = (bf16*)take((size_t)4096 * 768 * 2);
  bf16* O2B   = (bf16*)take((size_t)4096 * 768 * 2);
  float* YF   = (float*)take((size_t)4096 * 768 * 4);
  bf16* XBB   = (bf16*)take((size_t)4096 * 768 * 2);
  bf16* XTB   = (bf16*)take((size_t)768 * 4096 * 2);
  float* XN2  = (float*)take((size_t)4096 * 4);
  float* CB   = (float*)take((size_t)2 * 49152 * 4);
  bf16* CBH   = (bf16*)take((size_t)2 * 49152 * 2);
  bf16* ATB   = (bf16*)take((size_t)64 * 4096 * 2);
  float* CTRLF = (float*)take(8192 * 4);
  float* ASUM = CTRLF;
  float* CN   = CTRLF + 128;
  float* DIFF = CTRLF + 256;
  int* BAR    = (int*)(CTRLF + 512);

  float* aout = (float*)d_out + 49152;

  cvt_all<<<6528, 256, 0, stream>>>(x0, fc1w, fc2w, ipw, outw,
                                    X0B, W1B, FC2WB, IPWB, OUTWB, CTRLF);
  gemm128<1, 0, 0><<<dim3(32, 6), 256, 0, stream>>>(X0B, W1B, fc1b, HB, nullptr, 768, nullptr);
  gemm128<0, 0, 1><<<dim3(32, 18), 256, 0, stream>>>(HB, IPWB, ipb, QKVB, nullptr, 2304, VT);
  attn_kernel<<<768, 256, 0, stream>>>(QKVB, VT, OB);
  gemm128<0, 0, 0><<<dim3(32, 6), 256, 0, stream>>>(OB, OUTWB, outbias, O2B, nullptr, 768, nullptr);
  gemm128<1, 1, 0><<<dim3(32, 6), 256, 0, stream>>>(O2B, FC2WB, fc2b, nullptr, YF, 768, nullptr);
  ln_kernel<<<1024, 256, 0, stream>>>(x0, YF, lng, lnb, XBB, XN2);
  transpose_bf16<<<dim3(64, 12), 256, 0, stream>>>(XBB, XTB, 768, 0, 4096);
  dkm_fused<<<256, 256, 131072, stream>>>(idx, XBB, XTB, XN2, CB, CBH, ATB, aout,
                                          (float*)d_out, ASUM, CN, DIFF, BAR);
}